// Round 1
// baseline (142.303 us; speedup 1.0000x reference)
//
#include <hip/hip_runtime.h>

// Problem constants (fixed by setup_inputs): B=8, S=1024, E=128, H=32, DK=4.
constexpr int kS = 1024;
constexpr int kH = 32;

// ---------------------------------------------------------------------------
// K1: quantum encoder, collapsed analytically.
// chunk idx = (b*1024+s)*32 + head reads x4[idx] (coalesced float4),
// writes h[bh][s][4] with bh = b*32+head.
// z0=c1c2c3, z1=c0c1, z2=c0c1c2, z3=c0c1c2c3, c_w=cos(x_w + theta_w).
// ---------------------------------------------------------------------------
__global__ __launch_bounds__(256) void qenc_kernel(
    const float4* __restrict__ x4, const float* __restrict__ qp,
    float4* __restrict__ h4) {
  int idx = blockIdx.x * 256 + threadIdx.x;
  float4 a = x4[idx];
  float c0 = cosf(a.x + qp[0]);
  float c1 = cosf(a.y + qp[1]);
  float c2 = cosf(a.z + qp[2]);
  float c3 = cosf(a.w + qp[3]);
  float4 z;
  z.y = c0 * c1;
  z.z = z.y * c2;
  z.w = z.z * c3;
  z.x = c1 * c2 * c3;
  int b = idx >> 15;           // / (1024*32)
  int s = (idx >> 5) & (kS - 1);
  int head = idx & (kH - 1);
  h4[(((b * kH) + head) << 10) + s] = z;
}

// ---------------------------------------------------------------------------
// K2: attention for one (b,h) pair per 2 blocks. DK=4 so no max-subtraction
// is needed: |score| <= 2, exp(score) <= e^2. One-pass softmax+PV.
// Each thread owns 2 q-rows; k-loop reads h_k at a wave-uniform address.
// ---------------------------------------------------------------------------
__global__ __launch_bounds__(256) void attn_kernel(
    const float4* __restrict__ h4, float4* __restrict__ o4) {
  int bh = blockIdx.x >> 1;
  int qh = blockIdx.x & 1;
  const float4* __restrict__ hrow = h4 + (bh << 10);
  int q0 = (qh << 9) + threadIdx.x;
  int q1 = q0 + 256;
  float4 a0 = hrow[q0];
  float4 a1 = hrow[q1];
  const float sc = 0.72134752044448170f;  // 0.5 * log2(e): fold scale into q
  float4 b0 = make_float4(a0.x * sc, a0.y * sc, a0.z * sc, a0.w * sc);
  float4 b1 = make_float4(a1.x * sc, a1.y * sc, a1.z * sc, a1.w * sc);
  float4 acc0 = make_float4(0.f, 0.f, 0.f, 0.f);
  float4 acc1 = make_float4(0.f, 0.f, 0.f, 0.f);
  float l0 = 0.f, l1 = 0.f;
  for (int k = 0; k < kS; ++k) {
    float4 hk = hrow[k];  // wave-uniform -> scalar load
    float d0 = b0.x * hk.x + b0.y * hk.y + b0.z * hk.z + b0.w * hk.w;
    float d1 = b1.x * hk.x + b1.y * hk.y + b1.z * hk.z + b1.w * hk.w;
    float e0 = __builtin_amdgcn_exp2f(d0);
    float e1 = __builtin_amdgcn_exp2f(d1);
    acc0.x += e0 * hk.x; acc0.y += e0 * hk.y;
    acc0.z += e0 * hk.z; acc0.w += e0 * hk.w;
    acc1.x += e1 * hk.x; acc1.y += e1 * hk.y;
    acc1.z += e1 * hk.z; acc1.w += e1 * hk.w;
    l0 += e0;
    l1 += e1;
  }
  int b = bh >> 5, head = bh & 31;
  float r0 = 1.0f / l0, r1 = 1.0f / l1;
  o4[(((b << 10) + q0) << 5) + head] =
      make_float4(acc0.x * r0, acc0.y * r0, acc0.z * r0, acc0.w * r0);
  o4[(((b << 10) + q1) << 5) + head] =
      make_float4(acc1.x * r1, acc1.y * r1, acc1.z * r1, acc1.w * r1);
}

// ---------------------------------------------------------------------------
// K0: transpose W (128x128) so the combine GEMM reads coalesced.
// ---------------------------------------------------------------------------
__global__ __launch_bounds__(256) void wt_kernel(
    const float* __restrict__ W, float* __restrict__ WT) {
  int i = blockIdx.x * 256 + threadIdx.x;  // 16384 elems
  WT[(i & 127) * 128 + (i >> 7)] = W[i];
}

// ---------------------------------------------------------------------------
// K3: out[r][j] = sum_e o[r][e] * W[j][e] = sum_e o[r][e] * WT[e][j].
// Block = 32 rows staged in LDS; thread (rg=tid>>5, jg=tid&31) does 4 rows x
// 4 cols. WT float4 loads are lane-coalesced and L2-resident.
// ---------------------------------------------------------------------------
__global__ __launch_bounds__(256) void combine_kernel(
    const float* __restrict__ o, const float4* __restrict__ wt4,
    float4* __restrict__ out4) {
  __shared__ float so[32][128];
  int rbase = blockIdx.x * 32;
  const float4* o4 = (const float4*)o + rbase * 32;
  float4* so4 = (float4*)so;
  for (int t = threadIdx.x; t < 1024; t += 256) so4[t] = o4[t];
  __syncthreads();
  int jg = threadIdx.x & 31;
  int rg = threadIdx.x >> 5;  // 0..7 -> rows rg*4 .. rg*4+3
  float4 acc[4];
  acc[0] = acc[1] = acc[2] = acc[3] = make_float4(0.f, 0.f, 0.f, 0.f);
  for (int e = 0; e < 128; ++e) {
    float4 w = wt4[e * 32 + jg];
#pragma unroll
    for (int rr = 0; rr < 4; ++rr) {
      float ov = so[rg * 4 + rr][e];
      acc[rr].x += ov * w.x;
      acc[rr].y += ov * w.y;
      acc[rr].z += ov * w.z;
      acc[rr].w += ov * w.w;
    }
  }
#pragma unroll
  for (int rr = 0; rr < 4; ++rr)
    out4[(rbase + rg * 4 + rr) * 32 + jg] = acc[rr];
}

extern "C" void kernel_launch(void* const* d_in, const int* in_sizes, int n_in,
                              void* d_out, int out_size, void* d_ws,
                              size_t ws_size, hipStream_t stream) {
  const float* x = (const float*)d_in[0];        // [8,1024,128] f32
  const float* qp = (const float*)d_in[1];       // [1,4] f32
  const float* W = (const float*)d_in[2];        // [128,128] f32
  float* out = (float*)d_out;                    // [8,1024,128] f32

  char* ws = (char*)d_ws;
  float* h = (float*)ws;                  // [256][1024][4] f32 = 4 MB
  float* o = (float*)(ws + (4 << 20));    // [8][1024][128] f32 = 4 MB
  float* wt = (float*)(ws + (8 << 20));   // [128][128] f32 = 64 KB

  wt_kernel<<<64, 256, 0, stream>>>(W, wt);
  qenc_kernel<<<1024, 256, 0, stream>>>((const float4*)x, qp, (float4*)h);
  attn_kernel<<<512, 256, 0, stream>>>((const float4*)h, (float4*)o);
  combine_kernel<<<256, 256, 0, stream>>>(o, (const float4*)wt,
                                          (float4*)out);
}

// Round 2
// 124.572 us; speedup vs baseline: 1.1423x; 1.1423x over previous
//
#include <hip/hip_runtime.h>

// Problem constants (fixed by setup_inputs): B=8, S=1024, E=128, H=32, DK=4.
constexpr int kS = 1024;
constexpr int kH = 32;

// ---------------------------------------------------------------------------
// K1: quantum encoder, collapsed analytically.
// All RX gates commute into one RX per wire (angle x_w + theta_w) before the
// CNOT ring, which is a classical bit permutation. PauliZ expvals:
// z0=c1c2c3, z1=c0c1, z2=c0c1c2, z3=c0c1c2c3, c_w=cos(x_w + theta_w).
// ---------------------------------------------------------------------------
__global__ __launch_bounds__(256) void qenc_kernel(
    const float4* __restrict__ x4, const float* __restrict__ qp,
    float4* __restrict__ h4) {
  int idx = blockIdx.x * 256 + threadIdx.x;
  float4 a = x4[idx];
  float c0 = cosf(a.x + qp[0]);
  float c1 = cosf(a.y + qp[1]);
  float c2 = cosf(a.z + qp[2]);
  float c3 = cosf(a.w + qp[3]);
  float4 z;
  z.y = c0 * c1;
  z.z = z.y * c2;
  z.w = z.z * c3;
  z.x = c1 * c2 * c3;
  int b = idx >> 15;           // / (1024*32)
  int s = (idx >> 5) & (kS - 1);
  int head = idx & (kH - 1);
  h4[(((b * kH) + head) << 10) + s] = z;
}

// ---------------------------------------------------------------------------
// K2: attention. One (bh, q-chunk-of-256) per block, 1 q-row per thread.
// Grid = 256*4 = 1024 blocks = 4096 waves (4 waves/SIMD for latency hiding).
// DK=4 so |score| <= 2 -> exp2 needs no max subtraction. k-loop batches 8
// uniform hk loads into registers ahead of the math; dual accumulator chains
// halve the FMA dependency depth.
// ---------------------------------------------------------------------------
__global__ __launch_bounds__(256) void attn_kernel(
    const float4* __restrict__ h4, float4* __restrict__ o4) {
  int bh = blockIdx.x >> 2;
  int qc = blockIdx.x & 3;
  const float4* __restrict__ hrow = h4 + (bh << 10);
  int q = (qc << 8) + threadIdx.x;
  float4 a = hrow[q];
  const float sc = 0.72134752044448170f;  // 0.5 * log2(e): fold scale into q
  float4 b = make_float4(a.x * sc, a.y * sc, a.z * sc, a.w * sc);
  float4 accA = make_float4(0.f, 0.f, 0.f, 0.f);
  float4 accB = make_float4(0.f, 0.f, 0.f, 0.f);
  float lA = 0.f, lB = 0.f;
  for (int k0 = 0; k0 < kS; k0 += 8) {
    float4 hk[8];
#pragma unroll
    for (int j = 0; j < 8; ++j) hk[j] = hrow[k0 + j];
#pragma unroll
    for (int j = 0; j < 8; ++j) {
      float d = b.x * hk[j].x + b.y * hk[j].y + b.z * hk[j].z + b.w * hk[j].w;
      float e = __builtin_amdgcn_exp2f(d);
      if (j & 1) {
        accB.x += e * hk[j].x; accB.y += e * hk[j].y;
        accB.z += e * hk[j].z; accB.w += e * hk[j].w;
        lB += e;
      } else {
        accA.x += e * hk[j].x; accA.y += e * hk[j].y;
        accA.z += e * hk[j].z; accA.w += e * hk[j].w;
        lA += e;
      }
    }
  }
  float l = lA + lB;
  float r = 1.0f / l;
  float4 acc = make_float4((accA.x + accB.x) * r, (accA.y + accB.y) * r,
                           (accA.z + accB.z) * r, (accA.w + accB.w) * r);
  int b_ = bh >> 5, head = bh & 31;
  o4[(((b_ << 10) + q) << 5) + head] = acc;
}

// ---------------------------------------------------------------------------
// K0: transpose W (128x128) so the combine GEMM reads coalesced.
// ---------------------------------------------------------------------------
__global__ __launch_bounds__(256) void wt_kernel(
    const float* __restrict__ W, float* __restrict__ WT) {
  int i = blockIdx.x * 256 + threadIdx.x;  // 16384 elems
  WT[(i & 127) * 128 + (i >> 7)] = W[i];
}

// ---------------------------------------------------------------------------
// K3: out[r][j] = sum_e o[r][e] * WT[e][j]. Block = 32 rows staged in LDS;
// thread (rg=tid>>5, jg=tid&31) does 4 rows x 4 cols.
// ---------------------------------------------------------------------------
__global__ __launch_bounds__(256) void combine_kernel(
    const float* __restrict__ o, const float4* __restrict__ wt4,
    float4* __restrict__ out4) {
  __shared__ float so[32][128];
  int rbase = blockIdx.x * 32;
  const float4* o4 = (const float4*)o + rbase * 32;
  float4* so4 = (float4*)so;
  for (int t = threadIdx.x; t < 1024; t += 256) so4[t] = o4[t];
  __syncthreads();
  int jg = threadIdx.x & 31;
  int rg = threadIdx.x >> 5;  // 0..7 -> rows rg*4 .. rg*4+3
  float4 acc[4];
  acc[0] = acc[1] = acc[2] = acc[3] = make_float4(0.f, 0.f, 0.f, 0.f);
  for (int e = 0; e < 128; ++e) {
    float4 w = wt4[e * 32 + jg];
#pragma unroll
    for (int rr = 0; rr < 4; ++rr) {
      float ov = so[rg * 4 + rr][e];
      acc[rr].x += ov * w.x;
      acc[rr].y += ov * w.y;
      acc[rr].z += ov * w.z;
      acc[rr].w += ov * w.w;
    }
  }
#pragma unroll
  for (int rr = 0; rr < 4; ++rr)
    out4[(rbase + rg * 4 + rr) * 32 + jg] = acc[rr];
}

extern "C" void kernel_launch(void* const* d_in, const int* in_sizes, int n_in,
                              void* d_out, int out_size, void* d_ws,
                              size_t ws_size, hipStream_t stream) {
  const float* x = (const float*)d_in[0];        // [8,1024,128] f32
  const float* qp = (const float*)d_in[1];       // [1,4] f32
  const float* W = (const float*)d_in[2];        // [128,128] f32
  float* out = (float*)d_out;                    // [8,1024,128] f32

  char* ws = (char*)d_ws;
  float* h = (float*)ws;                  // [256][1024][4] f32 = 4 MB
  float* o = (float*)(ws + (4 << 20));    // [8][1024][128] f32 = 4 MB
  float* wt = (float*)(ws + (8 << 20));   // [128][128] f32 = 64 KB

  wt_kernel<<<64, 256, 0, stream>>>(W, wt);
  qenc_kernel<<<1024, 256, 0, stream>>>((const float4*)x, qp, (float4*)h);
  attn_kernel<<<1024, 256, 0, stream>>>((const float4*)h, (float4*)o);
  combine_kernel<<<256, 256, 0, stream>>>(o, (const float4*)wt,
                                          (float4*)out);
}

// Round 4
// 93.490 us; speedup vs baseline: 1.5221x; 1.3325x over previous
//
#include <hip/hip_runtime.h>

// Problem constants: B=8, S=1024, E=128, H=32, DK=4.
constexpr int kS = 1024;
constexpr int kH = 32;

typedef __fp16 fp16x2 __attribute__((ext_vector_type(2)));
typedef _Float16 half4v __attribute__((ext_vector_type(4)));
typedef _Float16 half8v __attribute__((ext_vector_type(8)));
typedef float float4v __attribute__((ext_vector_type(4)));

// ---------------------------------------------------------------------------
// K1: quantum encoder, collapsed analytically (verified rounds 1-2).
// z0=c1c2c3, z1=c0c1, z2=c0c1c2, z3=c0c1c2c3, c_w=cos(x_w + theta_w).
// Stores h16 = f16(z * sqrt(0.5*log2e)) so QK^T needs no per-tile scaling:
// (rs*q)·(rs*k) = 0.72134752*(q·k)  ->  exp2 of that = softmax numerator.
// ---------------------------------------------------------------------------
__global__ __launch_bounds__(256) void qenc_kernel(
    const float4* __restrict__ x4, const float* __restrict__ qp,
    half4v* __restrict__ h16) {
  int idx = blockIdx.x * 256 + threadIdx.x;
  float4 a = x4[idx];
  float c0 = cosf(a.x + qp[0]);
  float c1 = cosf(a.y + qp[1]);
  float c2 = cosf(a.z + qp[2]);
  float c3 = cosf(a.w + qp[3]);
  const float rs = 0.84932208f;  // sqrt(0.5*log2(e))
  float z1 = c0 * c1;
  float z2 = z1 * c2;
  float z3 = z2 * c3;
  float z0 = c1 * c2 * c3;
  half4v z16;
  z16.x = (_Float16)(z0 * rs);
  z16.y = (_Float16)(z1 * rs);
  z16.z = (_Float16)(z2 * rs);
  z16.w = (_Float16)(z3 * rs);
  int b = idx >> 15;
  int s = (idx >> 5) & (kS - 1);
  int head = idx & (kH - 1);
  h16[(((b * kH) + head) << 10) + s] = z16;
}

// ---------------------------------------------------------------------------
// K1b: build V-fragment layout hv[bh][k/4][d][j] = h16[bh][k4*4+j][d].
// hv carries h16's rs scale; the attn epilogue divides it back out.
// ---------------------------------------------------------------------------
__global__ __launch_bounds__(256) void hv_kernel(
    const ushort* __restrict__ h16u, ushort* __restrict__ hvu) {
  int bh = blockIdx.x;
  const ushort* src = h16u + (bh << 12);
  ushort* dst = hvu + (bh << 12);
  for (int k = threadIdx.x; k < 1024; k += 256) {
    ushort4 row = *(const ushort4*)(src + (k << 2));
    int base = ((k >> 2) << 4) + (k & 3);
    dst[base + 0] = row.x;
    dst[base + 4] = row.y;
    dst[base + 8] = row.z;
    dst[base + 12] = row.w;
  }
}

// ---------------------------------------------------------------------------
// K2: fused attention, f16 MFMA. One wave = one (bh, 16-q-row tile) job.
// Swapped QK^T: ST = mfma(A=K_chunk, B=Q_tile^T) -> ST[k][q] with C/D layout
// row=(lane>>4)*4+reg = k-in-chunk, col=lane&15 = q (guide-verified m89).
// exp2 on 4 regs -> cvt_pkrtz -> P-frag feeds PV mfma B-operand in place.
// PV: outT = mfma(A=V^T chunk, B=P) -> outT[d][q]; d=reg on lanes 0-15.
// Frag slot (g=lane>>4, j): k = k0 + 4g + j for both P and V (consistent
// relabeling of the 8-wide K-dim; slots j>=4 are zero on both sides).
// ---------------------------------------------------------------------------
__global__ __launch_bounds__(256) void attn_kernel(
    const _Float16* __restrict__ h16, const _Float16* __restrict__ hv,
    float4v* __restrict__ o4) {
  const int lane = threadIdx.x & 63;
  const int wv = threadIdx.x >> 6;
  const int job = blockIdx.x * 4 + wv;
  const int bh = job >> 6;
  const int q0 = (job & 63) << 4;
  const int r = lane & 15;
  const int g = lane >> 4;
  const bool act = (lane < 16);

  const uint2* hb2 = (const uint2*)(h16 + (bh << 12));  // [1024] rows of 8B
  const uint2* vb2 = (const uint2*)(hv + (bh << 12));   // [256*4] (k4,d) of 8B

  // Q fragment (B operand): lanes 0-15 hold h16[q0+r][0..3], rest zero.
  half8v qf;
  {
    uint2 qv = hb2[q0 + r];
    union { uint u[4]; half8v h; } uq = {{act ? qv.x : 0u, act ? qv.y : 0u, 0u, 0u}};
    qf = uq.h;
  }

  float4v acc = {0.f, 0.f, 0.f, 0.f};
  float lsum = 0.f;
  const int voff = (g << 2) + (r & 3);
  const bool vact = (r < 4);

#pragma unroll 4
  for (int k0 = 0; k0 < kS; k0 += 16) {
    uint2 kraw = hb2[k0 + r];
    uint2 vraw = vb2[k0 + voff];
    union { uint u[4]; half8v h; } uk = {{act ? kraw.x : 0u, act ? kraw.y : 0u, 0u, 0u}};
    union { uint u[4]; half8v h; } uv = {{vact ? vraw.x : 0u, vact ? vraw.y : 0u, 0u, 0u}};
    float4v st = __builtin_amdgcn_mfma_f32_16x16x32_f16(
        uk.h, qf, (float4v){0.f, 0.f, 0.f, 0.f}, 0, 0, 0);
    float e0 = __builtin_amdgcn_exp2f(st.x);
    float e1 = __builtin_amdgcn_exp2f(st.y);
    float e2 = __builtin_amdgcn_exp2f(st.z);
    float e3 = __builtin_amdgcn_exp2f(st.w);
    lsum += (e0 + e1) + (e2 + e3);
    union { fp16x2 h2[4]; half8v h; } up;
    up.h2[0] = __builtin_amdgcn_cvt_pkrtz(e0, e1);
    up.h2[1] = __builtin_amdgcn_cvt_pkrtz(e2, e3);
    up.h2[2] = (fp16x2)0;
    up.h2[3] = (fp16x2)0;
    acc = __builtin_amdgcn_mfma_f32_16x16x32_f16(uv.h, up.h, acc, 0, 0, 0);
  }

  // softmax denominator: sum partials across the 4 lane-groups.
  float lt = lsum;
  lt += __shfl_xor(lt, 16);
  lt += __shfl_xor(lt, 32);

  if (act) {
    // V was stored scaled by rs; undo it here: divide by (l * rs).
    const float inv_rs = 1.17740563f;  // 1/0.84932208
    float inv = inv_rs / lt;
    float4v res = {acc.x * inv, acc.y * inv, acc.z * inv, acc.w * inv};
    int b = bh >> 5, head = bh & 31;
    o4[(((b << 10) + q0 + r) << 5) + head] = res;
  }
}

// ---------------------------------------------------------------------------
// K0: transpose W (128x128) so the combine GEMM reads coalesced.
// ---------------------------------------------------------------------------
__global__ __launch_bounds__(256) void wt_kernel(
    const float* __restrict__ W, float* __restrict__ WT) {
  int i = blockIdx.x * 256 + threadIdx.x;
  WT[(i & 127) * 128 + (i >> 7)] = W[i];
}

// ---------------------------------------------------------------------------
// K3: out[r][j] = sum_e o[r][e] * WT[e][j]. 32 rows staged in LDS;
// thread (rg,jg) does 4 rows x 4 cols. (verified rounds 1-2)
// ---------------------------------------------------------------------------
__global__ __launch_bounds__(256) void combine_kernel(
    const float* __restrict__ o, const float4* __restrict__ wt4,
    float4* __restrict__ out4) {
  __shared__ float so[32][128];
  int rbase = blockIdx.x * 32;
  const float4* o4 = (const float4*)o + rbase * 32;
  float4* so4 = (float4*)so;
  for (int t = threadIdx.x; t < 1024; t += 256) so4[t] = o4[t];
  __syncthreads();
  int jg = threadIdx.x & 31;
  int rg = threadIdx.x >> 5;
  float4 acc[4];
  acc[0] = acc[1] = acc[2] = acc[3] = make_float4(0.f, 0.f, 0.f, 0.f);
  for (int e = 0; e < 128; ++e) {
    float4 w = wt4[e * 32 + jg];
#pragma unroll
    for (int rr = 0; rr < 4; ++rr) {
      float ov = so[rg * 4 + rr][e];
      acc[rr].x += ov * w.x;
      acc[rr].y += ov * w.y;
      acc[rr].z += ov * w.z;
      acc[rr].w += ov * w.w;
    }
  }
#pragma unroll
  for (int rr = 0; rr < 4; ++rr)
    out4[(rbase + rg * 4 + rr) * 32 + jg] = acc[rr];
}

extern "C" void kernel_launch(void* const* d_in, const int* in_sizes, int n_in,
                              void* d_out, int out_size, void* d_ws,
                              size_t ws_size, hipStream_t stream) {
  const float* x = (const float*)d_in[0];        // [8,1024,128] f32
  const float* qp = (const float*)d_in[1];       // [1,4] f32
  const float* W = (const float*)d_in[2];        // [128,128] f32
  float* out = (float*)d_out;                    // [8,1024,128] f32

  char* ws = (char*)d_ws;
  _Float16* h16 = (_Float16*)ws;                 // [256][1024][4] f16 = 2 MB
  _Float16* hv = (_Float16*)(ws + (2 << 20));    // [256][256][4][4] f16 = 2 MB
  float* o = (float*)(ws + (4 << 20));           // [8][1024][128] f32 = 4 MB
  float* wt = (float*)(ws + (8 << 20));          // [128][128] f32 = 64 KB

  wt_kernel<<<64, 256, 0, stream>>>(W, wt);
  qenc_kernel<<<1024, 256, 0, stream>>>((const float4*)x, qp, (half4v*)h16);
  hv_kernel<<<256, 256, 0, stream>>>((const ushort*)h16, (ushort*)hv);
  attn_kernel<<<4096, 256, 0, stream>>>(h16, hv, (float4v*)o);
  combine_kernel<<<256, 256, 0, stream>>>(o, (const float4*)wt,
                                          (float4*)out);
}

// Round 5
// 81.393 us; speedup vs baseline: 1.7483x; 1.1486x over previous
//
#include <hip/hip_runtime.h>

// Problem constants: B=8, S=1024, E=128, H=32, DK=4.
constexpr int kS = 1024;

typedef __fp16 fp16x2 __attribute__((ext_vector_type(2)));
typedef _Float16 half4v __attribute__((ext_vector_type(4)));
typedef float float4v __attribute__((ext_vector_type(4)));
typedef float float16v __attribute__((ext_vector_type(16)));

// ---------------------------------------------------------------------------
// K1: quantum encoder (analytic collapse, verified R1-R4) + fused V-transpose.
// h16[bh][s][d] = rs * z_d,  rs = sqrt(0.25*log2(e)) — the duplicate-K MFMA
// trick (see attn) doubles every dot, so exp2(ST) = e^{q·k/2} exactly.
// hv[bh][k4][d][j] = h16[bh][4*k4+j][d]  (V^T fragments for PV).
// ---------------------------------------------------------------------------
__global__ __launch_bounds__(256) void qenc_kernel(
    const float4* __restrict__ x4, const float* __restrict__ qp,
    uint2* __restrict__ h16u, ushort* __restrict__ hv) {
  int idx = blockIdx.x * 256 + threadIdx.x;
  float4 a = x4[idx];
  float c0 = cosf(a.x + qp[0]);
  float c1 = cosf(a.y + qp[1]);
  float c2 = cosf(a.z + qp[2]);
  float c3 = cosf(a.w + qp[3]);
  const float rs = 0.60056121f;  // sqrt(0.25*log2(e))
  float z1 = c0 * c1;
  float z2 = z1 * c2;
  float z3 = z2 * c3;
  float z0 = c1 * c2 * c3;
  union { half4v h; ushort4 us; uint2 u; } z;
  z.h.x = (_Float16)(z0 * rs);
  z.h.y = (_Float16)(z1 * rs);
  z.h.z = (_Float16)(z2 * rs);
  z.h.w = (_Float16)(z3 * rs);
  int b = idx >> 15;
  int s = (idx >> 5) & (kS - 1);
  int head = idx & 31;
  int bh = b * 32 + head;
  h16u[(bh << 10) + s] = z.u;
  int hb = (bh << 12) + ((s >> 2) << 4) + (s & 3);
  hv[hb + 0] = z.us.x;
  hv[hb + 4] = z.us.y;
  hv[hb + 8] = z.us.z;
  hv[hb + 12] = z.us.w;
}

// ---------------------------------------------------------------------------
// K2: fused attention on mfma_f32_32x32x8_f16. One wave = (bh, 32 q-rows).
// A-frag: lane l -> row=l&31, k=(l>>5)*4+j. No zeroing of hi lanes: both Q
// and K fragments duplicate dims 0-3 into k-slots 4-7 -> dot doubles
// (compensated in rs). ST C/D: col=lane&31=q, row=(reg&3)+8(reg>>2)+4hi=k'.
// ST regs [4c..4c+3] are EXACTLY the P-fragment for PV chunk c (K=8):
// lane needs P[k'=8c+4hi+b][q] = st reg 4c+b. Zero cross-lane traffic.
// V^T rows: d=0..3 from hv, row4 = 1.0 (softmax denominator for free in
// acc row 4 = reg0 of hi lanes), rows 5..31 = 0.
// ---------------------------------------------------------------------------
__global__ __launch_bounds__(256) void attn_kernel(
    const _Float16* __restrict__ h16, const _Float16* __restrict__ hv,
    float4v* __restrict__ o4) {
  const int lane = threadIdx.x & 63;
  const int wv = threadIdx.x >> 6;
  const int job = blockIdx.x * 4 + wv;
  const int bh = job >> 5;
  const int q0 = (job & 31) << 5;
  const int r = lane & 31;
  const int hi = lane >> 5;

  const uint2* __restrict__ hb2 = (const uint2*)(h16 + (bh << 12));
  const uint2* __restrict__ vb2 = (const uint2*)(hv + (bh << 12));

  union U2H { uint2 u; half4v h; };
  U2H uq;
  uq.u = hb2[q0 + r];  // duplicated across hi: intentional (2x dot trick)

  const bool vdat = (r < 4);
  const uint vfill = (r == 4) ? 0x3C003C00u : 0u;  // row4 = 1.0, rows 5+ = 0
  const int vbase = (hi << 2) + (r & 3);           // uint2 idx: k4*4 + d

  float16v acc = {};
  const float16v zero = {};

  for (int k0 = 0; k0 < kS; k0 += 32) {
    U2H uk;
    uk.u = hb2[k0 + r];
    uint2 vr0 = vb2[k0 + vbase];        // (k0>>2)*4 == k0
    uint2 vr1 = vb2[k0 + vbase + 8];
    uint2 vr2 = vb2[k0 + vbase + 16];
    uint2 vr3 = vb2[k0 + vbase + 24];
    float16v st =
        __builtin_amdgcn_mfma_f32_32x32x8f16(uk.h, uq.h, zero, 0, 0, 0);
#define PV_CHUNK(C, VR)                                                     \
  {                                                                         \
    float e0 = __builtin_amdgcn_exp2f(st[4 * C + 0]);                       \
    float e1 = __builtin_amdgcn_exp2f(st[4 * C + 1]);                       \
    float e2 = __builtin_amdgcn_exp2f(st[4 * C + 2]);                       \
    float e3 = __builtin_amdgcn_exp2f(st[4 * C + 3]);                       \
    union { fp16x2 p[2]; half4v h; } up;                                    \
    up.p[0] = __builtin_amdgcn_cvt_pkrtz(e0, e1);                           \
    up.p[1] = __builtin_amdgcn_cvt_pkrtz(e2, e3);                           \
    U2H uv;                                                                 \
    uv.u.x = vdat ? VR.x : vfill;                                           \
    uv.u.y = vdat ? VR.y : vfill;                                           \
    acc = __builtin_amdgcn_mfma_f32_32x32x8f16(uv.h, up.h, acc, 0, 0, 0);   \
  }
    PV_CHUNK(0, vr0)
    PV_CHUNK(1, vr1)
    PV_CHUNK(2, vr2)
    PV_CHUNK(3, vr3)
#undef PV_CHUNK
  }

  float denom = __shfl_xor(acc[0], 32);  // lanes 0-31 receive PV row 4 = sum P
  if (hi == 0) {
    const float inv_rs = 1.66510922f;  // V carries rs scale; undo once
    float inv = inv_rs / denom;
    float4v res = {acc[0] * inv, acc[1] * inv, acc[2] * inv, acc[3] * inv};
    int b = bh >> 5, head = bh & 31;
    o4[(((b << 10) + q0 + r) << 5) + head] = res;
  }
}

// ---------------------------------------------------------------------------
// K0: transpose W (128x128) so the combine GEMM reads coalesced.
// ---------------------------------------------------------------------------
__global__ __launch_bounds__(256) void wt_kernel(
    const float* __restrict__ W, float* __restrict__ WT) {
  int i = blockIdx.x * 256 + threadIdx.x;
  WT[(i & 127) * 128 + (i >> 7)] = W[i];
}

// ---------------------------------------------------------------------------
// K3: combine v2 — thread per (row, j-quad), 1024 blocks (4 blocks/CU, 16
// waves/CU vs old 1 block/CU latency-bound version). All operands L1/L2-hot.
// ---------------------------------------------------------------------------
__global__ __launch_bounds__(256) void combine_kernel(
    const float4* __restrict__ o4in, const float4* __restrict__ wt4,
    float4* __restrict__ out4) {
  int t = blockIdx.x * 256 + threadIdx.x;  // 262144 threads
  int j4 = t & 31;
  int row = t >> 5;
  const float4* orow = o4in + (row << 5);
  float4 acc = make_float4(0.f, 0.f, 0.f, 0.f);
  for (int e4 = 0; e4 < 32; ++e4) {
    float4 ov = orow[e4];
    float4 w0 = wt4[((e4 * 4 + 0) << 5) + j4];
    float4 w1 = wt4[((e4 * 4 + 1) << 5) + j4];
    float4 w2 = wt4[((e4 * 4 + 2) << 5) + j4];
    float4 w3 = wt4[((e4 * 4 + 3) << 5) + j4];
    acc.x += ov.x * w0.x + ov.y * w1.x + ov.z * w2.x + ov.w * w3.x;
    acc.y += ov.x * w0.y + ov.y * w1.y + ov.z * w2.y + ov.w * w3.y;
    acc.z += ov.x * w0.z + ov.y * w1.z + ov.z * w2.z + ov.w * w3.z;
    acc.w += ov.x * w0.w + ov.y * w1.w + ov.z * w2.w + ov.w * w3.w;
  }
  out4[(row << 5) + j4] = acc;
}

extern "C" void kernel_launch(void* const* d_in, const int* in_sizes, int n_in,
                              void* d_out, int out_size, void* d_ws,
                              size_t ws_size, hipStream_t stream) {
  const float* x = (const float*)d_in[0];   // [8,1024,128] f32
  const float* qp = (const float*)d_in[1];  // [1,4] f32
  const float* W = (const float*)d_in[2];   // [128,128] f32
  float* out = (float*)d_out;               // [8,1024,128] f32

  char* ws = (char*)d_ws;
  _Float16* h16 = (_Float16*)ws;               // [256][1024][4] f16 = 2 MB
  _Float16* hv = (_Float16*)(ws + (2 << 20));  // [256][256][4][4] f16 = 2 MB
  float* o = (float*)(ws + (4 << 20));         // [8][1024][128] f32 = 4 MB
  float* wt = (float*)(ws + (8 << 20));        // [128][128] f32 = 64 KB

  wt_kernel<<<64, 256, 0, stream>>>(W, wt);
  qenc_kernel<<<1024, 256, 0, stream>>>((const float4*)x, qp, (uint2*)h16,
                                        (ushort*)hv);
  attn_kernel<<<2048, 256, 0, stream>>>(h16, hv, (float4v*)o);
  combine_kernel<<<1024, 256, 0, stream>>>((const float4*)o, (const float4*)wt,
                                           (float4*)out);
}

// Round 6
// 64.716 us; speedup vs baseline: 2.1989x; 1.2577x over previous
//
#include <hip/hip_runtime.h>

// Problem constants: B=8, S=1024, E=128, H=32, DK=4.
constexpr int kS = 1024;

typedef __fp16 fp16x2 __attribute__((ext_vector_type(2)));
typedef _Float16 half4v __attribute__((ext_vector_type(4)));
typedef _Float16 half8v __attribute__((ext_vector_type(8)));
typedef float float4v __attribute__((ext_vector_type(4)));
typedef float float16v __attribute__((ext_vector_type(16)));

// ---------------------------------------------------------------------------
// K1: quantum encoder (analytic collapse, verified R1-R5).
// h16[bh][s][d] = rs*z_d, rs = sqrt(0.25*log2 e) (duplicate-K MFMA doubles the
// dot; exp2(ST) = e^{q.k/2} exactly).
// hvp[bh][kc][row][kslot]  (kc = key/8, kslot = key&7, f16):
//   rows 0-3 = rs*z_d (V^T data), row 4 = 1.0 (denominator row),
//   rows 5-7 = don't-care (PV output rows 5+ are never read).
// ---------------------------------------------------------------------------
__global__ __launch_bounds__(256) void qenc_kernel(
    const float4* __restrict__ x4, const float* __restrict__ qp,
    uint2* __restrict__ h16u, ushort* __restrict__ hvp,
    uint* __restrict__ hvpu) {
  int idx = blockIdx.x * 256 + threadIdx.x;
  float4 a = x4[idx];
  float c0 = cosf(a.x + qp[0]);
  float c1 = cosf(a.y + qp[1]);
  float c2 = cosf(a.z + qp[2]);
  float c3 = cosf(a.w + qp[3]);
  const float rs = 0.60056121f;  // sqrt(0.25*log2(e))
  float z1 = c0 * c1;
  float z2 = z1 * c2;
  float z3 = z2 * c3;
  float z0 = c1 * c2 * c3;
  union { half4v h; ushort4 us; uint2 u; } z;
  z.h.x = (_Float16)(z0 * rs);
  z.h.y = (_Float16)(z1 * rs);
  z.h.z = (_Float16)(z2 * rs);
  z.h.w = (_Float16)(z3 * rs);
  int b = idx >> 15;
  int s = (idx >> 5) & (kS - 1);
  int head = idx & 31;
  int bh = b * 32 + head;
  h16u[(bh << 10) + s] = z.u;
  // V^T data rows: hvp ushort idx = bh*8192 + kc*64 + row*8 + kslot
  int hb = (bh << 13) + ((s >> 3) << 6) + (s & 7);
  hvp[hb + 0] = z.us.x;
  hvp[hb + 8] = z.us.y;
  hvp[hb + 16] = z.us.z;
  hvp[hb + 24] = z.us.w;
  // row 4 = 1.0: per (bh,kc) uints 16..19; threads s<512 cover kc=s>>2,m=s&3.
  if (s < 512)
    hvpu[(bh << 12) + ((s >> 2) << 5) + 16 + (s & 3)] = 0x3C003C00u;
}

// ---------------------------------------------------------------------------
// K2: fused attention on mfma_f32_32x32x8_f16. One wave = (bh, 32 q-rows).
// A-frag: lane l -> row=l&31, kslot=(l>>5)*4+j. Q,K duplicate dims into both
// k-halves (2x dot folded into rs). ST C/D: col=lane&31=q,
// row=(reg&3)+8(reg>>2)+4hi=key'; ST regs [4c..4c+3] are exactly the P-frag
// for PV chunk c (K=8) on the same lane — zero cross-lane traffic.
// V-frag: all lanes load hvp row (r&7) — rows 0-3 data, row 4 ones (denom in
// PV row 4), rows 8-31 of the operand are duplicates (outputs unused).
// No cndmask anywhere in the loop.
// ---------------------------------------------------------------------------
__global__ __launch_bounds__(256) void attn_kernel(
    const _Float16* __restrict__ h16, const _Float16* __restrict__ hvp,
    uint2* __restrict__ o16u2) {
  const int lane = threadIdx.x & 63;
  const int wv = threadIdx.x >> 6;
  const int job = blockIdx.x * 4 + wv;
  const int bh = job >> 5;
  const int q0 = (job & 31) << 5;
  const int r = lane & 31;
  const int hi = lane >> 5;

  const uint2* __restrict__ hb2 = (const uint2*)(h16) + (bh << 10);
  const uint2* __restrict__ vb2 = (const uint2*)(hvp) + (bh << 11);

  union U2H { uint2 u; half4v h; };
  U2H uq;
  uq.u = hb2[q0 + r];

  const int vbase = ((r & 7) << 1) + hi;  // uint2 idx within a kc: row*2 + hi

  float16v acc = {};
  const float16v zero = {};

#pragma unroll 2
  for (int k0 = 0; k0 < kS; k0 += 32) {
    U2H uk;
    uk.u = hb2[k0 + r];
    uint2 vr0 = vb2[vbase + (k0 << 1)];
    uint2 vr1 = vb2[vbase + (k0 << 1) + 16];
    uint2 vr2 = vb2[vbase + (k0 << 1) + 32];
    uint2 vr3 = vb2[vbase + (k0 << 1) + 48];
    float16v st =
        __builtin_amdgcn_mfma_f32_32x32x8f16(uk.h, uq.h, zero, 0, 0, 0);
#define PV_CHUNK(C, VR)                                                   \
  {                                                                       \
    float e0 = __builtin_amdgcn_exp2f(st[4 * C + 0]);                     \
    float e1 = __builtin_amdgcn_exp2f(st[4 * C + 1]);                     \
    float e2 = __builtin_amdgcn_exp2f(st[4 * C + 2]);                     \
    float e3 = __builtin_amdgcn_exp2f(st[4 * C + 3]);                     \
    union { fp16x2 p[2]; half4v h; } up;                                  \
    up.p[0] = __builtin_amdgcn_cvt_pkrtz(e0, e1);                         \
    up.p[1] = __builtin_amdgcn_cvt_pkrtz(e2, e3);                         \
    U2H uv;                                                               \
    uv.u = VR;                                                            \
    acc = __builtin_amdgcn_mfma_f32_32x32x8f16(uv.h, up.h, acc, 0, 0, 0); \
  }
    PV_CHUNK(0, vr0)
    PV_CHUNK(1, vr1)
    PV_CHUNK(2, vr2)
    PV_CHUNK(3, vr3)
#undef PV_CHUNK
  }

  float denom = __shfl_xor(acc[0], 32);  // lanes 0-31 receive PV row4 = sum P
  if (hi == 0) {
    const float inv_rs = 1.66510922f;  // V carries rs scale; undo once
    float inv = inv_rs / denom;
    union { fp16x2 p[2]; uint2 u; } res;
    res.p[0] = __builtin_amdgcn_cvt_pkrtz(acc[0] * inv, acc[1] * inv);
    res.p[1] = __builtin_amdgcn_cvt_pkrtz(acc[2] * inv, acc[3] * inv);
    int b = bh >> 5, head = bh & 31;
    o16u2[(((b << 10) + q0 + r) << 5) + head] = res.u;
  }
}

// ---------------------------------------------------------------------------
// K0: pack W into B-fragment layout wtb[e>>3][col][e&7] (f16) for the
// combine MFMA: B[k=e][col] = W[col][e].
// ---------------------------------------------------------------------------
__global__ __launch_bounds__(256) void wtb_kernel(
    const float* __restrict__ W, _Float16* __restrict__ wtb) {
  int i = blockIdx.x * 256 + threadIdx.x;  // 16384
  int col = i >> 7, e = i & 127;
  wtb[((e >> 3) << 10) + (col << 3) + (e & 7)] = (_Float16)W[i];
}

// ---------------------------------------------------------------------------
// K3: combine GEMM out[8192][128] = o16 @ W^T via mfma_f32_16x16x32_f16.
// One wave per 16x16 tile: 512 row-tiles x 8 col-tiles = 4096 waves.
// A slot (g,j): e = t*32+g*8+j (contiguous 16B row loads); B uses the same
// labeling via wtb — slot-consistent contraction.
// ---------------------------------------------------------------------------
__global__ __launch_bounds__(256) void combine_kernel(
    const _Float16* __restrict__ o16, const _Float16* __restrict__ wtb,
    float* __restrict__ out) {
  const int lane = threadIdx.x & 63;
  const int wv = threadIdx.x >> 6;
  const int job = blockIdx.x * 4 + wv;  // 0..4095
  const int rt = job >> 3, ct = job & 7;
  const int c = lane & 15, g = lane >> 4;
  const uint4* a4 = (const uint4*)o16;
  const uint4* b4 = (const uint4*)wtb;
  const int arow = (rt << 4) + c;
  union U4H { uint4 u; half8v h; };
  float4v acc = {};
#pragma unroll
  for (int t = 0; t < 4; ++t) {
    U4H ua, ub;
    ua.u = a4[(arow << 4) + (t << 2) + g];
    ub.u = b4[(((t << 2) + g) << 7) + (ct << 4) + c];
    acc = __builtin_amdgcn_mfma_f32_16x16x32_f16(ua.h, ub.h, acc, 0, 0, 0);
  }
  const int orow = (rt << 4) + (g << 2);
  const int ocol = (ct << 4) + c;
#pragma unroll
  for (int reg = 0; reg < 4; ++reg)
    out[(orow + reg) * 128 + ocol] = acc[reg];
}

extern "C" void kernel_launch(void* const* d_in, const int* in_sizes, int n_in,
                              void* d_out, int out_size, void* d_ws,
                              size_t ws_size, hipStream_t stream) {
  const float* x = (const float*)d_in[0];   // [8,1024,128] f32
  const float* qp = (const float*)d_in[1];  // [1,4] f32
  const float* W = (const float*)d_in[2];   // [128,128] f32
  float* out = (float*)d_out;               // [8,1024,128] f32

  char* ws = (char*)d_ws;
  _Float16* h16 = (_Float16*)ws;                // [256][1024][4] f16 = 2 MB
  _Float16* hvp = (_Float16*)(ws + (2 << 20));  // [256][128][8][8] f16 = 4 MB
  _Float16* o16 = (_Float16*)(ws + (6 << 20));  // [8192][128] f16 = 2 MB
  _Float16* wtb = (_Float16*)(ws + (8 << 20));  // [16][128][8] f16 = 32 KB

  wtb_kernel<<<64, 256, 0, stream>>>(W, wtb);
  qenc_kernel<<<1024, 256, 0, stream>>>((const float4*)x, qp, (uint2*)h16,
                                        (ushort*)hvp, (uint*)hvp);
  attn_kernel<<<2048, 256, 0, stream>>>(h16, hvp, (uint2*)o16);
  combine_kernel<<<1024, 256, 0, stream>>>(o16, wtb, out);
}

// Round 8
// 64.596 us; speedup vs baseline: 2.2030x; 1.0019x over previous
//
#include <hip/hip_runtime.h>

// Problem constants: B=8, S=1024, E=128, H=32, DK=4.
constexpr int kS = 1024;

typedef __fp16 fp16x2 __attribute__((ext_vector_type(2)));
typedef _Float16 half4v __attribute__((ext_vector_type(4)));
typedef _Float16 half8v __attribute__((ext_vector_type(8)));
typedef float float4v __attribute__((ext_vector_type(4)));
typedef float float16v __attribute__((ext_vector_type(16)));

// ---------------------------------------------------------------------------
// K1: quantum encoder (analytic collapse, verified R1-R6).
// h16[bh][s][d] = rs*z_d, rs = sqrt(0.25*0.72134752): the x16 MFMA duplicates
// dims 4x on both operands -> ST = 4*rs^2*(z_q.z_k) = (q.k)/2 * log2(e).
// hvq[bh][kb(32)][chunk(2)][row(8)][hi(2)][j(8)] f16 (V^T fragments):
//   key = kb*32 + chunk*16 + kappa(hi,j), kappa = (j&3) + 8*(j>>2) + 4*hi.
//   rows 0-3 = rs*z_d, row 4 = 1.0 (denominator row), rows 5-7 don't-care.
// ---------------------------------------------------------------------------
__global__ __launch_bounds__(256) void qenc_kernel(
    const float4* __restrict__ x4, const float* __restrict__ qp,
    uint2* __restrict__ h16u, ushort* __restrict__ hvq,
    uint* __restrict__ hvqu) {
  int idx = blockIdx.x * 256 + threadIdx.x;
  float4 a = x4[idx];
  float c0 = cosf(a.x + qp[0]);
  float c1 = cosf(a.y + qp[1]);
  float c2 = cosf(a.z + qp[2]);
  float c3 = cosf(a.w + qp[3]);
  const float rs = 0.42466104f;  // sqrt(0.25 * 0.5 * log2(e))
  float z1 = c0 * c1;
  float z2 = z1 * c2;
  float z3 = z2 * c3;
  float z0 = c1 * c2 * c3;
  union { half4v h; ushort4 us; uint2 u; } z;
  z.h.x = (_Float16)(z0 * rs);
  z.h.y = (_Float16)(z1 * rs);
  z.h.z = (_Float16)(z2 * rs);
  z.h.w = (_Float16)(z3 * rs);
  int b = idx >> 15;
  int s = (idx >> 5) & (kS - 1);
  int head = idx & 31;
  int bh = b * 32 + head;
  h16u[(bh << 10) + s] = z.u;
  // V^T scatter: key s -> (kb, chunk, hi, j)
  int kb = s >> 5, kk = s & 31;
  int chunk = (kk >> 4) & 1, kk4 = kk & 15;
  int hi = (kk4 >> 2) & 1;
  int j = (kk4 & 3) + ((kk4 >> 3) << 2);
  int base = (bh << 13) + (kb << 8) + (chunk << 7) + (hi << 3) + j;
  hvq[base + 0] = z.us.x;   // row 0
  hvq[base + 16] = z.us.y;  // row 1
  hvq[base + 32] = z.us.z;  // row 2
  hvq[base + 48] = z.us.w;  // row 3
  // row 4 = 1.0: 4 uints per (kb,chunk,hi); threads s<512 cover them.
  if (s < 512) {
    int t = s;
    int ukb = t >> 4, uch = (t >> 3) & 1, uhi = (t >> 2) & 1, m = t & 3;
    hvqu[(bh << 12) + (ukb << 7) + (uch << 6) + 32 + (uhi << 2) + m] =
        0x3C003C00u;
  }
}

// ---------------------------------------------------------------------------
// K2: fused attention on mfma_f32_32x32x16_f16 (the fast CDNA4 shape).
// One wave = (bh, 32 q-rows). QK^T: A=K-frag, B=Q-frag, both with dims 0-3
// duplicated into all 16 k-slots in groups of 4 (dot x4, folded into rs).
// ST C/D (verified m74/m101): col=lane&31=q, key'=(reg&3)+8*(reg>>2)+4*hi;
// regs 0-7 = keys kappa(hi,j) of chunk 0, regs 8-15 = chunk 1 — so the PV
// B-frag for chunk c is exactly cvt_pkrtz(ST regs 8c..8c+7) on every lane.
// Both P and V place key 16c+kappa(hi,j) at slot (j,hi): the contraction
// pairs matching keys for ANY hw slot->k bijection.
// A-frag for PV = hvq rows (r&7): rows 0-3 V data, row 4 ones (denominator
// lands in acc row 4 = reg 0 of hi=1 lanes), rows 5-7 don't-care.
// ---------------------------------------------------------------------------
__global__ __launch_bounds__(256) void attn_kernel(
    const _Float16* __restrict__ h16, const _Float16* __restrict__ hvq,
    uint2* __restrict__ o16u2) {
  const int lane = threadIdx.x & 63;
  const int wv = threadIdx.x >> 6;
  const int job = blockIdx.x * 4 + wv;
  const int bh = job >> 5;
  const int q0 = (job & 31) << 5;
  const int r = lane & 31;
  const int hi = lane >> 5;

  const uint2* __restrict__ hb2 = (const uint2*)(h16) + (bh << 10);
  // R7 BUG WAS HERE: hvq is 1024 uint4 per bh -> stride bh<<10 (was bh<<9).
  const uint4* __restrict__ vb4 = (const uint4*)(hvq) + (bh << 10);

  union U4H { uint4 u; half8v h; };
  U4H uq;
  {
    uint2 qv = hb2[q0 + r];
    uq.u.x = qv.x; uq.u.y = qv.y; uq.u.z = qv.x; uq.u.w = qv.y;
  }

  const int vbase = ((r & 7) << 1) + hi;  // uint4 idx within kb: row*2 + hi

  float16v acc = {};
  const float16v zero = {};

#pragma unroll 2
  for (int k0 = 0; k0 < kS; k0 += 32) {
    U4H uk;
    {
      uint2 kv = hb2[k0 + r];
      uk.u.x = kv.x; uk.u.y = kv.y; uk.u.z = kv.x; uk.u.w = kv.y;
    }
    const int kb32 = k0;  // kb*32 (uint4 units per kb = 32)
    U4H uv0, uv1;
    uv0.u = vb4[kb32 + vbase];
    uv1.u = vb4[kb32 + 16 + vbase];
    float16v st =
        __builtin_amdgcn_mfma_f32_32x32x16_f16(uk.h, uq.h, zero, 0, 0, 0);
#define PV_CHUNK(C, UV)                                                    \
  {                                                                        \
    union { fp16x2 p[4]; half8v h; } up;                                   \
    up.p[0] = __builtin_amdgcn_cvt_pkrtz(                                  \
        __builtin_amdgcn_exp2f(st[8 * C + 0]),                             \
        __builtin_amdgcn_exp2f(st[8 * C + 1]));                            \
    up.p[1] = __builtin_amdgcn_cvt_pkrtz(                                  \
        __builtin_amdgcn_exp2f(st[8 * C + 2]),                             \
        __builtin_amdgcn_exp2f(st[8 * C + 3]));                            \
    up.p[2] = __builtin_amdgcn_cvt_pkrtz(                                  \
        __builtin_amdgcn_exp2f(st[8 * C + 4]),                             \
        __builtin_amdgcn_exp2f(st[8 * C + 5]));                            \
    up.p[3] = __builtin_amdgcn_cvt_pkrtz(                                  \
        __builtin_amdgcn_exp2f(st[8 * C + 6]),                             \
        __builtin_amdgcn_exp2f(st[8 * C + 7]));                            \
    acc = __builtin_amdgcn_mfma_f32_32x32x16_f16(UV.h, up.h, acc, 0, 0, 0); \
  }
    PV_CHUNK(0, uv0)
    PV_CHUNK(1, uv1)
#undef PV_CHUNK
  }

  float denom = __shfl_xor(acc[0], 32);  // lanes 0-31 get PV row 4 = sum P
  if (hi == 0) {
    const float inv_rs = 2.35481780f;  // 1/rs: V carries rs scale; undo once
    float inv = inv_rs / denom;
    union { fp16x2 p[2]; uint2 u; } res;
    res.p[0] = __builtin_amdgcn_cvt_pkrtz(acc[0] * inv, acc[1] * inv);
    res.p[1] = __builtin_amdgcn_cvt_pkrtz(acc[2] * inv, acc[3] * inv);
    int b = bh >> 5, head = bh & 31;
    o16u2[(((b << 10) + q0 + r) << 5) + head] = res.u;
  }
}

// ---------------------------------------------------------------------------
// K0: pack W into B-fragment layout wtb[e>>3][col][e&7] (f16) for the
// combine MFMA: B[k=e][col] = W[col][e].
// ---------------------------------------------------------------------------
__global__ __launch_bounds__(256) void wtb_kernel(
    const float* __restrict__ W, _Float16* __restrict__ wtb) {
  int i = blockIdx.x * 256 + threadIdx.x;  // 16384
  int col = i >> 7, e = i & 127;
  wtb[((e >> 3) << 10) + (col << 3) + (e & 7)] = (_Float16)W[i];
}

// ---------------------------------------------------------------------------
// K3: combine GEMM out[8192][128] = o16 @ W^T via mfma_f32_16x16x32_f16.
// One wave per 16x16 tile: 512 row-tiles x 8 col-tiles = 4096 waves.
// (verified R6: ~3 us)
// ---------------------------------------------------------------------------
__global__ __launch_bounds__(256) void combine_kernel(
    const _Float16* __restrict__ o16, const _Float16* __restrict__ wtb,
    float* __restrict__ out) {
  const int lane = threadIdx.x & 63;
  const int wv = threadIdx.x >> 6;
  const int job = blockIdx.x * 4 + wv;  // 0..4095
  const int rt = job >> 3, ct = job & 7;
  const int c = lane & 15, g = lane >> 4;
  const uint4* a4 = (const uint4*)o16;
  const uint4* b4 = (const uint4*)wtb;
  const int arow = (rt << 4) + c;
  union U4H { uint4 u; half8v h; };
  float4v acc = {};
#pragma unroll
  for (int t = 0; t < 4; ++t) {
    U4H ua, ub;
    ua.u = a4[(arow << 4) + (t << 2) + g];
    ub.u = b4[(((t << 2) + g) << 7) + (ct << 4) + c];
    acc = __builtin_amdgcn_mfma_f32_16x16x32_f16(ua.h, ub.h, acc, 0, 0, 0);
  }
  const int orow = (rt << 4) + (g << 2);
  const int ocol = (ct << 4) + c;
#pragma unroll
  for (int reg = 0; reg < 4; ++reg)
    out[(orow + reg) * 128 + ocol] = acc[reg];
}

extern "C" void kernel_launch(void* const* d_in, const int* in_sizes, int n_in,
                              void* d_out, int out_size, void* d_ws,
                              size_t ws_size, hipStream_t stream) {
  const float* x = (const float*)d_in[0];   // [8,1024,128] f32
  const float* qp = (const float*)d_in[1];  // [1,4] f32
  const float* W = (const float*)d_in[2];   // [128,128] f32
  float* out = (float*)d_out;               // [8,1024,128] f32

  char* ws = (char*)d_ws;
  _Float16* h16 = (_Float16*)ws;                // [256][1024][4] f16 = 2 MB
  _Float16* hvq = (_Float16*)(ws + (2 << 20));  // [256][32][2][8][2][8] = 4 MB
  _Float16* o16 = (_Float16*)(ws + (6 << 20));  // [8192][128] f16 = 2 MB
  _Float16* wtb = (_Float16*)(ws + (8 << 20));  // [16][128][8] f16 = 32 KB

  wtb_kernel<<<64, 256, 0, stream>>>(W, wtb);
  qenc_kernel<<<1024, 256, 0, stream>>>((const float4*)x, qp, (uint2*)h16,
                                        (ushort*)hvq, (uint*)hvq);
  attn_kernel<<<2048, 256, 0, stream>>>(h16, hvq, (uint2*)o16);
  combine_kernel<<<1024, 256, 0, stream>>>(o16, wtb, out);
}